// Round 5
// baseline (410.388 us; speedup 1.0000x reference)
//
#include <hip/hip_runtime.h>

typedef float v4f __attribute__((ext_vector_type(4)));

#define RAD 3
#define TW  256              // tile width  (64 lanes x 4 cols)
#define TH  16               // tile height (4 waves x 4 rows, 2 rows/step)
#define LROWS (TH + 2*RAD)   // 22
#define PITCH 264            // LDS row pitch (floats); row bytes 1056 = 66*16 (b128-aligned)

#define LOG2E 1.4426950408889634f
#define KC2   (-50.0f * LOG2E)          // color coeff, pre-scaled by log2(e)
#define SSC   (LOG2E / 18.0f)           // spatial coeff, pre-scaled
#define SARG(dy,dx) (-(float)(((dy)-3)*((dy)-3) + ((dx)-3)*((dx)-3)) * SSC)

__device__ __forceinline__ float fexp2(float x) { return __builtin_amdgcn_exp2f(x); }

__global__ __launch_bounds__(256) void bilateral_kernel(
    const float* __restrict__ in, float* __restrict__ out, int H, int W)
{
    __shared__ float tile[LROWS * PITCH];

    const int tx = threadIdx.x;              // 0..63
    const int ty = threadIdx.y;              // 0..3 (wave id)
    const int gx0 = blockIdx.x * TW;
    const int gy0 = blockIdx.y * TH;
    const size_t plane = (size_t)blockIdx.z * H * W;
    const float* __restrict__ p = in + plane;
    float* __restrict__ q = out + plane;

    // ---- Stage 22 x 264 tile (tile col c <-> global col gx0 + c - 4) ----
    const bool xedge = (blockIdx.x == 0) || (blockIdx.x == gridDim.x - 1);
    for (int r = ty; r < LROWS; r += 4) {
        const int gy = min(max(gy0 + r - RAD, 0), H - 1);
        const float* rp = p + (size_t)gy * W;
        for (int qd = tx; qd < PITCH / 4; qd += 64) {
            const int gc = gx0 - 4 + 4 * qd;
            v4f val;
            if (!xedge || (gc >= 0 && gc + 3 < W)) {
                val = *reinterpret_cast<const v4f*>(rp + gc);
            } else {
                #pragma unroll
                for (int e = 0; e < 4; ++e) {
                    const int c = min(max(gc + e, 0), W - 1);
                    val[e] = rp[c];
                }
            }
            *reinterpret_cast<v4f*>(&tile[r * PITCH + 4 * qd]) = val;
        }
    }
    __syncthreads();

    // Each wave owns rows [4*ty, 4*ty+4); 2 steps of a vertical pixel pair.
    #pragma unroll 1
    for (int step = 0; step < 2; ++step) {
        const int ory = ty * 4 + step * 2;   // output rows ory, ory+1 (tile-relative)

        // Centers: tile rows ory+3 / ory+4, tile cols 4tx+4 .. 4tx+7
        const v4f xc0 = *reinterpret_cast<const v4f*>(&tile[(ory + 3) * PITCH + 4 * tx + 4]);
        const v4f xc1 = *reinterpret_cast<const v4f*>(&tile[(ory + 4) * PITCH + 4 * tx + 4]);

        float b0[4], cb0[4], b1[4], cb1[4];
        float num0[4], den0[4], num1[4], den1[4];
        #pragma unroll
        for (int pp = 0; pp < 4; ++pp) {
            const float xa = xc0[pp], xb = xc1[pp];
            b0[pp]  = -2.0f * KC2 * xa;  cb0[pp] = KC2 * xa * xa;
            b1[pp]  = -2.0f * KC2 * xb;  cb1[pp] = KC2 * xb * xb;
            // center tap (dy=3,dx=3): arg==0 exactly -> w==1: fold into init
            num0[pp] = xa;  den0[pp] = 1.0f;
            num1[pp] = xb;  den1[pp] = 1.0f;
        }

        // Sample row ory+rr serves center0 at dy=rr (rr<=6) and center1 at dy=rr-1 (rr>=1)
        #pragma unroll
        for (int rr = 0; rr < 8; ++rr) {
            const float* rowp = &tile[(ory + rr) * PITCH + 4 * tx];
            const v4f ra = *reinterpret_cast<const v4f*>(rowp);
            const v4f rb = *reinterpret_cast<const v4f*>(rowp + 4);
            const v4f rc = *reinterpret_cast<const v4f*>(rowp + 8);
            const float v[12] = {ra.x, ra.y, ra.z, ra.w,
                                 rb.x, rb.y, rb.z, rb.w,
                                 rc.x, rc.y, rc.z, rc.w};

            #pragma unroll
            for (int dx = 0; dx < 7; ++dx) {
                #pragma unroll
                for (int pp = 0; pp < 4; ++pp) {
                    const float s = v[1 + pp + dx];
                    if (rr < 7 && !(rr == 3 && dx == 3)) {       // center0 tap
                        const float t = fmaf(KC2, s, b0[pp]);
                        const float a = fmaf(s, t, cb0[pp] + SARG(rr, dx));
                        const float w = fexp2(a);
                        num0[pp] = fmaf(w, s, num0[pp]);
                        den0[pp] += w;
                    }
                    if (rr >= 1 && !(rr == 4 && dx == 3)) {      // center1 tap
                        const float t = fmaf(KC2, s, b1[pp]);
                        const float a = fmaf(s, t, cb1[pp] + SARG(rr - 1, dx));
                        const float w = fexp2(a);
                        num1[pp] = fmaf(w, s, num1[pp]);
                        den1[pp] += w;
                    }
                }
            }
        }

        v4f o0, o1;
        #pragma unroll
        for (int pp = 0; pp < 4; ++pp) {
            o0[pp] = num0[pp] * __builtin_amdgcn_rcpf(den0[pp]);
            o1[pp] = num1[pp] * __builtin_amdgcn_rcpf(den1[pp]);
        }
        float* q0 = q + (size_t)(gy0 + ory) * W + gx0 + 4 * tx;
        *reinterpret_cast<v4f*>(q0)     = o0;
        *reinterpret_cast<v4f*>(q0 + W) = o1;
    }
}

extern "C" void kernel_launch(void* const* d_in, const int* in_sizes, int n_in,
                              void* d_out, int out_size, void* d_ws, size_t ws_size,
                              hipStream_t stream)
{
    const float* in = (const float*)d_in[0];
    float* out = (float*)d_out;

    const int H = 1024, W = 1024;
    const int planes = in_sizes[0] / (H * W);       // 48

    dim3 grid(W / TW, H / TH, planes);              // 4 x 64 x 48
    dim3 block(64, 4, 1);
    bilateral_kernel<<<grid, block, 0, stream>>>(in, out, H, W);
}